// Round 1
// baseline (428.610 us; speedup 1.0000x reference)
//
#include <hip/hip_runtime.h>

// GraphSAGE: 4 SAGEConv layers (sum-aggregate) + MLP head.
// Trick: agg @ Wl.T == scatter-add of (h @ Wl.T)[src], so the scatter always
// moves 16 floats/edge. acc is initialized with bl + Wr*h, scatter adds the
// neighbor term, and the next layer's dense kernel applies silu on read.

__device__ __forceinline__ float silu_f(float v) {
    return v / (1.0f + __expf(-v));
}

template <int DIN_, bool SILU_IN>
__global__ __launch_bounds__(256) void sage_dense(
    const float* __restrict__ hin,   // [n, DIN_] (pre-activation if SILU_IN)
    const float* __restrict__ Wl,    // [16, DIN_]
    const float* __restrict__ bl,    // [16]
    const float* __restrict__ Wr,    // [16, DIN_]
    float* __restrict__ hl,          // out: [n,16] = Wl * act(hin)
    float* __restrict__ acc,         // out: [n,16] = bl + Wr * act(hin)
    int n)
{
    __shared__ float sWl[16 * DIN_];
    __shared__ float sWr[16 * DIN_];
    __shared__ float sbl[16];
    __shared__ float sx[256][DIN_ + 1];   // +1 pad: kill bank conflicts

    const int t = threadIdx.x;
    for (int i = t; i < 16 * DIN_; i += 256) { sWl[i] = Wl[i]; sWr[i] = Wr[i]; }
    if (t < 16) sbl[t] = bl[t];

    const int base = blockIdx.x * 256;
    // cooperative, coalesced load of 256 input rows
    for (int i = t; i < 256 * DIN_; i += 256) {
        const int r = i / DIN_, c = i % DIN_;
        const int node = base + r;
        sx[r][c] = (node < n) ? hin[(size_t)node * DIN_ + c] : 0.0f;
    }
    __syncthreads();

    const int node = base + t;
    if (node >= n) return;

    float h[DIN_];
#pragma unroll
    for (int d = 0; d < DIN_; ++d) {
        float v = sx[t][d];
        h[d] = SILU_IN ? silu_f(v) : v;
    }

#pragma unroll
    for (int j = 0; j < 16; ++j) {
        float al = 0.0f, ar = 0.0f;
#pragma unroll
        for (int d = 0; d < DIN_; ++d) {
            al = fmaf(sWl[j * DIN_ + d], h[d], al);
            ar = fmaf(sWr[j * DIN_ + d], h[d], ar);
        }
        hl[(size_t)node * 16 + j]  = al;
        acc[(size_t)node * 16 + j] = sbl[j] + ar;
    }
}

__global__ __launch_bounds__(256) void sage_scatter(
    const int* __restrict__ src, const int* __restrict__ dst,
    const float* __restrict__ hl, float* __restrict__ acc, int ne)
{
    const int t = blockIdx.x * 256 + threadIdx.x;
    const int e = t >> 4;
    if (e >= ne) return;
    const int j = t & 15;
    const int s = src[e];
    const int d = dst[e];
    const float v = hl[(size_t)s * 16 + j];
    unsafeAtomicAdd(&acc[(size_t)d * 16 + j], v);
}

__global__ __launch_bounds__(256) void final_mlp(
    const float* __restrict__ accin,  // [n,16] pre-activation
    const float* __restrict__ W1, const float* __restrict__ b1,  // [32,16],[32]
    const float* __restrict__ W2, const float* __restrict__ b2,  // [32,32],[32]
    const float* __restrict__ W3, const float* __restrict__ b3,  // [1,32],[1]
    float* __restrict__ out, int n)
{
    __shared__ float sW1[32 * 16];
    __shared__ float sW2[32 * 32];
    __shared__ float sb1[32], sb2[32], sW3[32];
    __shared__ float sb3;

    const int t = threadIdx.x;
    for (int i = t; i < 32 * 16; i += 256) sW1[i] = W1[i];
    for (int i = t; i < 32 * 32; i += 256) sW2[i] = W2[i];
    if (t < 32) { sb1[t] = b1[t]; sb2[t] = b2[t]; sW3[t] = W3[t]; }
    if (t == 0) sb3 = b3[0];
    __syncthreads();

    const int node = blockIdx.x * 256 + t;
    if (node >= n) return;

    float h[16];
#pragma unroll
    for (int d = 0; d < 16; ++d) h[d] = silu_f(accin[(size_t)node * 16 + d]);

    float a1[32];
#pragma unroll
    for (int j = 0; j < 32; ++j) {
        float s = sb1[j];
#pragma unroll
        for (int d = 0; d < 16; ++d) s = fmaf(sW1[j * 16 + d], h[d], s);
        a1[j] = silu_f(s);
    }

    float o = sb3;
#pragma unroll
    for (int j = 0; j < 32; ++j) {
        float s = sb2[j];
#pragma unroll
        for (int d = 0; d < 32; ++d) s = fmaf(sW2[j * 32 + d], a1[d], s);
        o = fmaf(sW3[j], silu_f(s), o);
    }
    out[node] = o;
}

extern "C" void kernel_launch(void* const* d_in, const int* in_sizes, int n_in,
                              void* d_out, int out_size, void* d_ws, size_t ws_size,
                              hipStream_t stream)
{
    const float* x   = (const float*)d_in[0];
    const int*   ei  = (const int*)d_in[1];
    const float* Wl0 = (const float*)d_in[2];
    const float* bl0 = (const float*)d_in[3];
    const float* Wr0 = (const float*)d_in[4];
    const float* Wls = (const float*)d_in[5];   // [3,16,16]
    const float* bls = (const float*)d_in[6];   // [3,16]
    const float* Wrs = (const float*)d_in[7];   // [3,16,16]
    const float* W1  = (const float*)d_in[8];
    const float* b1  = (const float*)d_in[9];
    const float* W2  = (const float*)d_in[10];
    const float* b2  = (const float*)d_in[11];
    const float* W3  = (const float*)d_in[12];
    const float* b3  = (const float*)d_in[13];

    const int n  = in_sizes[0] / 32;   // N nodes
    const int ne = in_sizes[1] / 2;    // E edges
    const int* src = ei;
    const int* dst = ei + ne;

    float* hl   = (float*)d_ws;               // [n,16]
    float* acc0 = hl + (size_t)n * 16;        // [n,16]
    float* acc1 = acc0 + (size_t)n * 16;      // [n,16]

    const int nb = (n + 255) / 256;
    const int eb = (int)(((long long)ne * 16 + 255) / 256);

    // layer 0: 32 -> 16, no input activation
    sage_dense<32, false><<<nb, 256, 0, stream>>>(x, Wl0, bl0, Wr0, hl, acc0, n);
    sage_scatter<<<eb, 256, 0, stream>>>(src, dst, hl, acc0, ne);
    // layer 1
    sage_dense<16, true><<<nb, 256, 0, stream>>>(acc0, Wls + 0,   bls + 0,  Wrs + 0,   hl, acc1, n);
    sage_scatter<<<eb, 256, 0, stream>>>(src, dst, hl, acc1, ne);
    // layer 2
    sage_dense<16, true><<<nb, 256, 0, stream>>>(acc1, Wls + 256, bls + 16, Wrs + 256, hl, acc0, n);
    sage_scatter<<<eb, 256, 0, stream>>>(src, dst, hl, acc0, ne);
    // layer 3
    sage_dense<16, true><<<nb, 256, 0, stream>>>(acc0, Wls + 512, bls + 32, Wrs + 512, hl, acc1, n);
    sage_scatter<<<eb, 256, 0, stream>>>(src, dst, hl, acc1, ne);
    // head
    final_mlp<<<nb, 256, 0, stream>>>(acc1, W1, b1, W2, b2, W3, b3, (float*)d_out, n);
}

// Round 2
// 389.011 us; speedup vs baseline: 1.1018x; 1.1018x over previous
//
#include <hip/hip_runtime.h>

// GraphSAGE 4×SAGEConv + MLP head, fp32.
// R2: replace float-atomic scatter (100 MB/layer HBM write-through, 84 us/layer)
// with per-call CSR build + gather aggregation (plain loads, 6.4 MB writes/layer).
// Linear-before-scatter trick retained: agg @ Wl.T == gather-sum of (h @ Wl.T).

__device__ __forceinline__ float silu_f(float v) {
    return v / (1.0f + __expf(-v));
}

// ---------------- CSR build ----------------

__global__ __launch_bounds__(256) void hist_kernel(
    const int* __restrict__ dst, int* __restrict__ counts, int ne)
{
    const int e = blockIdx.x * 256 + threadIdx.x;
    if (e < ne) atomicAdd(&counts[dst[e]], 1);
}

// per-block exclusive scan of counts -> offsets (partial), block totals -> bsums
__global__ __launch_bounds__(256) void scan1(
    const int* __restrict__ counts, int* __restrict__ offsets,
    int* __restrict__ bsums, int n)
{
    __shared__ int sh[256];
    const int t = threadIdx.x;
    const int i = blockIdx.x * 256 + t;
    const int c = (i < n) ? counts[i] : 0;
    sh[t] = c;
    __syncthreads();
    int v = c;
    for (int off = 1; off < 256; off <<= 1) {
        const int add = (t >= off) ? sh[t - off] : 0;
        __syncthreads();
        v += add;
        sh[t] = v;
        __syncthreads();
    }
    if (i < n) offsets[i] = v - c;           // exclusive within block
    if (t == 255) bsums[blockIdx.x] = v;     // block total
}

// exclusive scan of block sums (nb <= 512) in one block
__global__ __launch_bounds__(512) void scan2(int* __restrict__ bsums, int nb)
{
    __shared__ int sh[512];
    const int t = threadIdx.x;
    const int c = (t < nb) ? bsums[t] : 0;
    sh[t] = c;
    __syncthreads();
    int v = c;
    for (int off = 1; off < 512; off <<= 1) {
        const int add = (t >= off) ? sh[t - off] : 0;
        __syncthreads();
        v += add;
        sh[t] = v;
        __syncthreads();
    }
    if (t < nb) bsums[t] = v - c;            // exclusive
}

__global__ __launch_bounds__(256) void scan3(
    int* __restrict__ offsets, const int* __restrict__ bsums, int n, int ne)
{
    const int i = blockIdx.x * 256 + threadIdx.x;
    if (i < n) offsets[i] += bsums[blockIdx.x];
    if (i == 0) offsets[n] = ne;
}

// counts doubles as a reverse cursor (atomicSub), ends at 0
__global__ __launch_bounds__(256) void fill_kernel(
    const int* __restrict__ src, const int* __restrict__ dst,
    const int* __restrict__ offsets, int* __restrict__ counts,
    int* __restrict__ eidx, int ne)
{
    const int e = blockIdx.x * 256 + threadIdx.x;
    if (e >= ne) return;
    const int d = dst[e];
    const int r = atomicSub(&counts[d], 1) - 1;
    eidx[offsets[d] + r] = src[e];
}

// ---------------- layers ----------------

// acc[node] += sum over in-neighbors of hl[src]; 4 lanes/node, float4 each
__global__ __launch_bounds__(256) void sage_agg(
    const int* __restrict__ offsets, const int* __restrict__ eidx,
    const float* __restrict__ hl, float* __restrict__ acc, int n)
{
    const int tid = blockIdx.x * 256 + threadIdx.x;
    const int node = tid >> 2;
    if (node >= n) return;
    const int q = tid & 3;
    const int beg = offsets[node];
    const int end = offsets[node + 1];
    const float4* __restrict__ h4 = (const float4*)hl;
    float4 s = {0.f, 0.f, 0.f, 0.f};
    for (int k = beg; k < end; ++k) {
        const int sN = eidx[k];
        const float4 v = h4[(size_t)sN * 4 + q];
        s.x += v.x; s.y += v.y; s.z += v.z; s.w += v.w;
    }
    float4* __restrict__ a4 = (float4*)acc;
    float4 a = a4[(size_t)node * 4 + q];
    a.x += s.x; a.y += s.y; a.z += s.z; a.w += s.w;
    a4[(size_t)node * 4 + q] = a;
}

template <int DIN_, bool SILU_IN>
__global__ __launch_bounds__(256) void sage_dense(
    const float* __restrict__ hin,   // [n, DIN_] (pre-activation if SILU_IN)
    const float* __restrict__ Wl,    // [16, DIN_]
    const float* __restrict__ bl,    // [16]
    const float* __restrict__ Wr,    // [16, DIN_]
    float* __restrict__ hl,          // out: [n,16] = Wl * act(hin)
    float* __restrict__ acc,         // out: [n,16] = bl + Wr * act(hin)
    int n)
{
    __shared__ float sWl[16 * DIN_];
    __shared__ float sWr[16 * DIN_];
    __shared__ float sbl[16];

    const int t = threadIdx.x;
    for (int i = t; i < 16 * DIN_; i += 256) { sWl[i] = Wl[i]; sWr[i] = Wr[i]; }
    if (t < 16) sbl[t] = bl[t];
    __syncthreads();

    const int node = blockIdx.x * 256 + t;
    if (node >= n) return;

    float h[DIN_];
    const float4* __restrict__ xp = (const float4*)(hin + (size_t)node * DIN_);
#pragma unroll
    for (int q = 0; q < DIN_ / 4; ++q) {
        const float4 v = xp[q];
        h[q * 4 + 0] = v.x; h[q * 4 + 1] = v.y;
        h[q * 4 + 2] = v.z; h[q * 4 + 3] = v.w;
    }
    if (SILU_IN) {
#pragma unroll
        for (int d = 0; d < DIN_; ++d) h[d] = silu_f(h[d]);
    }

    float ol[16], oa[16];
#pragma unroll
    for (int j = 0; j < 16; ++j) {
        float al = 0.0f, ar = 0.0f;
#pragma unroll
        for (int d = 0; d < DIN_; ++d) {
            al = fmaf(sWl[j * DIN_ + d], h[d], al);
            ar = fmaf(sWr[j * DIN_ + d], h[d], ar);
        }
        ol[j] = al;
        oa[j] = sbl[j] + ar;
    }

    float4* __restrict__ hp = (float4*)(hl + (size_t)node * 16);
    float4* __restrict__ ap = (float4*)(acc + (size_t)node * 16);
#pragma unroll
    for (int q = 0; q < 4; ++q) {
        hp[q] = make_float4(ol[q * 4], ol[q * 4 + 1], ol[q * 4 + 2], ol[q * 4 + 3]);
        ap[q] = make_float4(oa[q * 4], oa[q * 4 + 1], oa[q * 4 + 2], oa[q * 4 + 3]);
    }
}

__global__ __launch_bounds__(256) void final_mlp(
    const float* __restrict__ accin,  // [n,16] pre-activation
    const float* __restrict__ W1, const float* __restrict__ b1,  // [32,16],[32]
    const float* __restrict__ W2, const float* __restrict__ b2,  // [32,32],[32]
    const float* __restrict__ W3, const float* __restrict__ b3,  // [1,32],[1]
    float* __restrict__ out, int n)
{
    __shared__ float sW1[32 * 16];
    __shared__ float sW2[32 * 32];
    __shared__ float sb1[32], sb2[32], sW3[32];
    __shared__ float sb3;

    const int t = threadIdx.x;
    for (int i = t; i < 32 * 16; i += 256) sW1[i] = W1[i];
    for (int i = t; i < 32 * 32; i += 256) sW2[i] = W2[i];
    if (t < 32) { sb1[t] = b1[t]; sb2[t] = b2[t]; sW3[t] = W3[t]; }
    if (t == 0) sb3 = b3[0];
    __syncthreads();

    const int node = blockIdx.x * 256 + t;
    if (node >= n) return;

    float h[16];
    const float4* __restrict__ xp = (const float4*)(accin + (size_t)node * 16);
#pragma unroll
    for (int q = 0; q < 4; ++q) {
        const float4 v = xp[q];
        h[q * 4 + 0] = silu_f(v.x); h[q * 4 + 1] = silu_f(v.y);
        h[q * 4 + 2] = silu_f(v.z); h[q * 4 + 3] = silu_f(v.w);
    }

    float a1[32];
#pragma unroll
    for (int j = 0; j < 32; ++j) {
        float s = sb1[j];
#pragma unroll
        for (int d = 0; d < 16; ++d) s = fmaf(sW1[j * 16 + d], h[d], s);
        a1[j] = silu_f(s);
    }

    float o = sb3;
#pragma unroll
    for (int j = 0; j < 32; ++j) {
        float s = sb2[j];
#pragma unroll
        for (int d = 0; d < 32; ++d) s = fmaf(sW2[j * 32 + d], a1[d], s);
        o = fmaf(sW3[j], silu_f(s), o);
    }
    out[node] = o;
}

extern "C" void kernel_launch(void* const* d_in, const int* in_sizes, int n_in,
                              void* d_out, int out_size, void* d_ws, size_t ws_size,
                              hipStream_t stream)
{
    const float* x   = (const float*)d_in[0];
    const int*   ei  = (const int*)d_in[1];
    const float* Wl0 = (const float*)d_in[2];
    const float* bl0 = (const float*)d_in[3];
    const float* Wr0 = (const float*)d_in[4];
    const float* Wls = (const float*)d_in[5];   // [3,16,16]
    const float* bls = (const float*)d_in[6];   // [3,16]
    const float* Wrs = (const float*)d_in[7];   // [3,16,16]
    const float* W1  = (const float*)d_in[8];
    const float* b1  = (const float*)d_in[9];
    const float* W2  = (const float*)d_in[10];
    const float* b2  = (const float*)d_in[11];
    const float* W3  = (const float*)d_in[12];
    const float* b3  = (const float*)d_in[13];

    const int n  = in_sizes[0] / 32;   // N nodes
    const int ne = in_sizes[1] / 2;    // E edges
    const int* src = ei;
    const int* dst = ei + ne;

    // workspace carve-up
    float* hl   = (float*)d_ws;                    // [n,16]
    float* acc0 = hl + (size_t)n * 16;             // [n,16]
    float* acc1 = acc0 + (size_t)n * 16;           // [n,16]
    int* offsets = (int*)(acc1 + (size_t)n * 16);  // [n+1]
    int* counts  = offsets + (n + 2);              // [n] (histogram, then reverse cursor)
    int* bsums   = counts + n;                     // [<=512]
    int* eidx    = bsums + 512;                    // [ne]

    const int nb  = (n + 255) / 256;               // node blocks (=scan blocks)
    const int ebk = (ne + 255) / 256;              // edge blocks
    const int ab  = (n * 4 + 255) / 256;           // agg blocks (4 lanes/node)

    // ---- CSR build ----
    hipMemsetAsync(counts, 0, (size_t)n * sizeof(int), stream);
    hist_kernel<<<ebk, 256, 0, stream>>>(dst, counts, ne);
    scan1<<<nb, 256, 0, stream>>>(counts, offsets, bsums, n);
    scan2<<<1, 512, 0, stream>>>(bsums, nb);
    scan3<<<nb, 256, 0, stream>>>(offsets, bsums, n, ne);
    fill_kernel<<<ebk, 256, 0, stream>>>(src, dst, offsets, counts, eidx, ne);

    // ---- layers ----
    sage_dense<32, false><<<nb, 256, 0, stream>>>(x, Wl0, bl0, Wr0, hl, acc0, n);
    sage_agg<<<ab, 256, 0, stream>>>(offsets, eidx, hl, acc0, n);

    sage_dense<16, true><<<nb, 256, 0, stream>>>(acc0, Wls + 0,   bls + 0,  Wrs + 0,   hl, acc1, n);
    sage_agg<<<ab, 256, 0, stream>>>(offsets, eidx, hl, acc1, n);

    sage_dense<16, true><<<nb, 256, 0, stream>>>(acc1, Wls + 256, bls + 16, Wrs + 256, hl, acc0, n);
    sage_agg<<<ab, 256, 0, stream>>>(offsets, eidx, hl, acc0, n);

    sage_dense<16, true><<<nb, 256, 0, stream>>>(acc0, Wls + 512, bls + 32, Wrs + 512, hl, acc1, n);
    sage_agg<<<ab, 256, 0, stream>>>(offsets, eidx, hl, acc1, n);

    final_mlp<<<nb, 256, 0, stream>>>(acc1, W1, b1, W2, b2, W3, b3, (float*)d_out, n);
}